// Round 3
// baseline (788.063 us; speedup 1.0000x reference)
//
#include <hip/hip_runtime.h>

#define NN 50000
#define NE 800000
#define DDIM 64
#define PADX 68          // fp32 LDS row stride (node pool)
#define PADS 68          // fp32 per-wave scratch stride (rows are 272 B -> 16B aligned, odd*4 banks)
#define NB_SCAN ((NN + 255) / 256)   // 196
#define NEG_SLOPE 0.2f
#define EPS_V 1e-5f

#define NGROUPS (NE / 32)            // 25000 dst-sorted 32-edge groups
#define NWAVES_E 4096                // 1024 blocks x 4 waves (exactly 4 blocks/CU, one fill)
#define GQ (NGROUPS / NWAVES_E)      // 6
#define GR (NGROUPS - NWAVES_E * GQ) // 424 waves get GQ+1 groups

typedef short bf16x8 __attribute__((ext_vector_type(8)));
typedef float f32x4 __attribute__((ext_vector_type(4)));

__device__ __forceinline__ float lrelu_f(float x) { return x >= 0.0f ? x : NEG_SLOPE * x; }

__device__ __forceinline__ unsigned short bf16_rn(float x) {
    union { float f; unsigned int u; } c; c.f = x;
    unsigned int r = c.u + 0x7FFF + ((c.u >> 16) & 1);
    return (unsigned short)(r >> 16);
}
__device__ __forceinline__ float bf16_tof(unsigned short h) {
    union { float f; unsigned int u; } c; c.u = ((unsigned int)h) << 16;
    return c.f;
}

// packed bf16 convert (RNE), 2 f32 -> u32 [lo=bf16(a) | hi=bf16(b)]
__device__ __forceinline__ unsigned cvtpk_bf16(float a, float b) {
    unsigned r;
    asm("v_cvt_pk_bf16_f32 %0, %1, %2" : "=v"(r) : "v"(a), "v"(b));
    return r;
}

// split 8 fp32 -> hi/lo bf16x8 (RNE both; ~2^-18 effective rel err) via v_cvt_pk_bf16_f32
__device__ __forceinline__ void split8(const float* __restrict__ v, bf16x8& h, bf16x8& l)
{
    union { bf16x8 v8; unsigned u[4]; } H, L;
    #pragma unroll
    for (int k = 0; k < 4; ++k) {
        float a = v[2*k], b = v[2*k+1];
        unsigned p = cvtpk_bf16(a, b);
        union { float f; unsigned u; } h0, h1;
        h0.u = p << 16;
        h1.u = p & 0xFFFF0000u;
        unsigned q = cvtpk_bf16(a - h0.f, b - h1.f);
        H.u[k] = p;
        L.u[k] = q;
    }
    h = H.v8; l = L.v8;
}

// ---------------- fp32 micro-tile GEMM helpers (node pooling only) ----------------
__device__ __forceinline__ void mma_tile(float acc[16], const float* __restrict__ XT,
                                         const float* __restrict__ Wc, int e0, int f0)
{
    #pragma unroll 4
    for (int kk = 0; kk < DDIM; kk += 4) {
        float4 A0 = *(const float4*)&XT[(kk+0)*PADX + e0];
        float4 A1 = *(const float4*)&XT[(kk+1)*PADX + e0];
        float4 A2 = *(const float4*)&XT[(kk+2)*PADX + e0];
        float4 A3 = *(const float4*)&XT[(kk+3)*PADX + e0];
        float4 B0 = *(const float4*)&Wc[(f0+0)*PADX + kk];
        float4 B1 = *(const float4*)&Wc[(f0+1)*PADX + kk];
        float4 B2 = *(const float4*)&Wc[(f0+2)*PADX + kk];
        float4 B3 = *(const float4*)&Wc[(f0+3)*PADX + kk];
        const float a[4][4] = {{A0.x,A0.y,A0.z,A0.w},{A1.x,A1.y,A1.z,A1.w},
                               {A2.x,A2.y,A2.z,A2.w},{A3.x,A3.y,A3.z,A3.w}};
        const float b[4][4] = {{B0.x,B0.y,B0.z,B0.w},{B1.x,B1.y,B1.z,B1.w},
                               {B2.x,B2.y,B2.z,B2.w},{B3.x,B3.y,B3.z,B3.w}};
        #pragma unroll
        for (int j = 0; j < 4; ++j)
            #pragma unroll
            for (int i = 0; i < 4; ++i)
                #pragma unroll
                for (int q = 0; q < 4; ++q)
                    acc[i*4+j] = fmaf(a[q][i], b[j][q], acc[i*4+j]);
    }
}

__device__ __forceinline__ void load_w_f32(float* __restrict__ Wc, const float* __restrict__ Wg, int tid)
{
    #pragma unroll
    for (int c = 0; c < 4; ++c) {
        int idx = (c << 10) + (tid << 2);
        int f = idx >> 6, k = idx & 63;
        *(float4*)&Wc[f*PADX + k] = *(const float4*)&Wg[idx];
    }
}

// ---------------- node pooling (fp32) + fused dst histogram ----------------
__global__ __launch_bounds__(256, 3)
void node_pool_kernel(const float* __restrict__ V,
                      const float* __restrict__ Aw, const float* __restrict__ Ab,
                      const float* __restrict__ Bw, const float* __restrict__ Bbv,
                      float* __restrict__ Vp,
                      const int* __restrict__ dst, int* __restrict__ degi)
{
    __shared__ float Wc[DDIM*PADX];
    __shared__ float XT[DDIM*PADX];
    const int tid = threadIdx.x;
    const int nb = blockIdx.x * 64;
    const int e0 = (tid & 15) << 2;
    const int f0 = (tid >> 4) << 2;

    #pragma unroll
    for (int c = 0; c < 4; ++c) {
        int idx = (c << 10) + (tid << 2);
        int e = idx >> 6, d = idx & 63;
        int row = nb + e; if (row > NN-1) row = NN-1;
        float4 v = *(const float4*)&V[(size_t)row*DDIM + d];
        XT[(d+0)*PADX + e] = lrelu_f(v.x);
        XT[(d+1)*PADX + e] = lrelu_f(v.y);
        XT[(d+2)*PADX + e] = lrelu_f(v.z);
        XT[(d+3)*PADX + e] = lrelu_f(v.w);
    }
    load_w_f32(Wc, Aw, tid);
    __syncthreads();

    float acc[16];
    #pragma unroll
    for (int i = 0; i < 16; ++i) acc[i] = 0.f;
    mma_tile(acc, XT, Wc, e0, f0);
    __syncthreads();

    {   // lrelu(acc + Ab) -> XT
        float4 bv = *(const float4*)&Ab[f0];
        const float ba[4] = {bv.x, bv.y, bv.z, bv.w};
        #pragma unroll
        for (int j = 0; j < 4; ++j) {
            float4 v;
            v.x = lrelu_f(acc[0*4+j] + ba[j]);
            v.y = lrelu_f(acc[1*4+j] + ba[j]);
            v.z = lrelu_f(acc[2*4+j] + ba[j]);
            v.w = lrelu_f(acc[3*4+j] + ba[j]);
            *(float4*)&XT[(f0+j)*PADX + e0] = v;
        }
    }
    load_w_f32(Wc, Bw, tid);
    __syncthreads();

    float acc2[16];
    #pragma unroll
    for (int i = 0; i < 16; ++i) acc2[i] = 0.f;
    mma_tile(acc2, XT, Wc, e0, f0);

    float4 bv = *(const float4*)&Bbv[f0];
    #pragma unroll
    for (int i = 0; i < 4; ++i) {
        int row = nb + e0 + i;
        if (row < NN) {
            float4 o;
            o.x = acc2[i*4+0] + bv.x;
            o.y = acc2[i*4+1] + bv.y;
            o.z = acc2[i*4+2] + bv.z;
            o.w = acc2[i*4+3] + bv.w;
            *(float4*)&Vp[(size_t)row*DDIM + f0] = o;
        }
    }

    // fused histogram tail: grid-stride over edges
    const int stride = gridDim.x * 256;
    for (int e = blockIdx.x * 256 + tid; e < NE; e += stride)
        atomicAdd(&degi[dst[e]], 1);
}

// ---------------- split-bf16 weight fragment precompute ----------------
// Layout: WF[L][t][ks][hl][lane][j] shorts; per-layer stride 8192 shorts.
// lane: n=lane&15 (feature col), kg=lane>>4; f=t*16+n; k=ks*32+kg*8+j.
__global__ __launch_bounds__(256)
void prep_w_kernel(const float* __restrict__ W1, const float* __restrict__ W2,
                   const float* __restrict__ WB, const float* __restrict__ WC,
                   short* __restrict__ WF)
{
    int gid = blockIdx.x * 256 + threadIdx.x;   // grid = 64 blocks -> 16384 threads
    int L = gid >> 12, r = gid & 4095;
    int t = r >> 10, ks = (r >> 9) & 1, lane = (r >> 3) & 63, j = r & 7;
    const float* Ws = (L == 0) ? W1 : (L == 1) ? W2 : (L == 2) ? WB : WC;
    int n = lane & 15, kg = lane >> 4;
    int f = t*16 + n, k = ks*32 + kg*8 + j;
    float v = Ws[f*64 + k];
    unsigned short h = bf16_rn(v);
    unsigned short l = bf16_rn(v - bf16_tof(h));
    int base = L*8192 + ((t*2 + ks)*2)*512 + lane*8 + j;
    WF[base]       = (short)h;
    WF[base + 512] = (short)l;
}

// ---------------- CSR build: scan / scatter ----------------
__global__ __launch_bounds__(256)
void scan1_kernel(const int* __restrict__ degi, int* __restrict__ linc, int* __restrict__ bsum)
{
    __shared__ int ws[4];
    const int tid = threadIdx.x;
    const int lane = tid & 63, wv = tid >> 6;
    int i = blockIdx.x * 256 + tid;
    int v = (i < NN) ? degi[i] : 0;
    int sc = v;
    #pragma unroll
    for (int off = 1; off < 64; off <<= 1) {
        int t = __shfl_up(sc, off, 64);
        if (lane >= off) sc += t;
    }
    if (lane == 63) ws[wv] = sc;
    __syncthreads();
    int wb = 0;
    #pragma unroll
    for (int w = 0; w < 4; ++w) if (w < wv) wb += ws[w];
    int incl = sc + wb;
    if (i < NN) linc[i] = incl;
    if (tid == 255) bsum[blockIdx.x] = incl;
}

__global__ __launch_bounds__(256)
void scan23_kernel(const int* __restrict__ degi, const int* __restrict__ linc,
                   const int* __restrict__ bsum, int* __restrict__ curs)
{
    __shared__ int ws[4];
    __shared__ int base_s;
    const int tid = threadIdx.x;
    const int lane = tid & 63, wv = tid >> 6;
    int v = (tid < NB_SCAN) ? bsum[tid] : 0;
    int sc = v;
    #pragma unroll
    for (int off = 1; off < 64; off <<= 1) {
        int t = __shfl_up(sc, off, 64);
        if (lane >= off) sc += t;
    }
    if (lane == 63) ws[wv] = sc;
    __syncthreads();
    int wb = 0;
    #pragma unroll
    for (int w = 0; w < 4; ++w) if (w < wv) wb += ws[w];
    if (tid == blockIdx.x) base_s = sc + wb - v;
    __syncthreads();
    int i = blockIdx.x * 256 + tid;
    if (i < NN) curs[i] = base_s + linc[i] - degi[i];
}

__global__ __launch_bounds__(256)
void scatter_kernel(const int* __restrict__ dst, int* __restrict__ cursor, int* __restrict__ eidx)
{
    int e = blockIdx.x * 256 + threadIdx.x;
    if (e < NE) {
        int p = atomicAdd(&cursor[dst[e]], 1);
        eidx[p] = e;
    }
}

// ---------------- barrier-free per-wave split-bf16 MFMA edge kernel ----------------
// Dual-tile GEMM: weight fragments loaded ONCE per (ks) serve both 16-row tiles.
__device__ __forceinline__ void gemm64_dual(const short* __restrict__ WL, int lane,
                                            const bf16x8 ah0[2], const bf16x8 al0[2],
                                            const bf16x8 ah1[2], const bf16x8 al1[2],
                                            f32x4 acc0[4], f32x4 acc1[4])
{
    #pragma unroll
    for (int ks = 0; ks < 2; ++ks) {
        bf16x8 bh[4], bl[4];
        #pragma unroll
        for (int t = 0; t < 4; ++t) {
            bh[t] = *(const bf16x8*)&WL[(((t*2 + ks)*2 + 0)*64 + lane)*8];
            bl[t] = *(const bf16x8*)&WL[(((t*2 + ks)*2 + 1)*64 + lane)*8];
        }
        #pragma unroll
        for (int t = 0; t < 4; ++t) {
            acc0[t] = __builtin_amdgcn_mfma_f32_16x16x32_bf16(al0[ks], bh[t], acc0[t], 0, 0, 0);
            acc1[t] = __builtin_amdgcn_mfma_f32_16x16x32_bf16(al1[ks], bh[t], acc1[t], 0, 0, 0);
            acc0[t] = __builtin_amdgcn_mfma_f32_16x16x32_bf16(ah0[ks], bl[t], acc0[t], 0, 0, 0);
            acc1[t] = __builtin_amdgcn_mfma_f32_16x16x32_bf16(ah1[ks], bl[t], acc1[t], 0, 0, 0);
            acc0[t] = __builtin_amdgcn_mfma_f32_16x16x32_bf16(ah0[ks], bh[t], acc0[t], 0, 0, 0);
            acc1[t] = __builtin_amdgcn_mfma_f32_16x16x32_bf16(ah1[ks], bh[t], acc1[t], 0, 0, 0);
        }
    }
}

// D-layout y[t][r] for both tiles -> per-wave 32-row LDS -> A-frags for next layer.
// Wave-lockstep: DS ops from one wave complete in order; no __syncthreads needed.
__device__ __forceinline__ void transpose_frags_dual(float* __restrict__ sw,
                                                     const f32x4 y0[4], const f32x4 y1[4],
                                                     int lane,
                                                     bf16x8 ah0[2], bf16x8 al0[2],
                                                     bf16x8 ah1[2], bf16x8 al1[2])
{
    const int n = lane & 15, mg = lane >> 4;
    #pragma unroll
    for (int t = 0; t < 4; ++t)
        #pragma unroll
        for (int r = 0; r < 4; ++r) {
            sw[(mg*4 + r)*PADS + t*16 + n]      = y0[t][r];
            sw[(16 + mg*4 + r)*PADS + t*16 + n] = y1[t][r];
        }
    __builtin_amdgcn_wave_barrier();
    const int m = lane & 15, kg = lane >> 4;   // m: edge row, kg: k-group
    {
        float x[16];
        *(float4*)&x[0]  = *(const float4*)&sw[m*PADS + kg*8];
        *(float4*)&x[4]  = *(const float4*)&sw[m*PADS + kg*8 + 4];
        *(float4*)&x[8]  = *(const float4*)&sw[m*PADS + 32 + kg*8];
        *(float4*)&x[12] = *(const float4*)&sw[m*PADS + 32 + kg*8 + 4];
        split8(&x[0], ah0[0], al0[0]);
        split8(&x[8], ah0[1], al0[1]);
    }
    {
        float x[16];
        *(float4*)&x[0]  = *(const float4*)&sw[(16+m)*PADS + kg*8];
        *(float4*)&x[4]  = *(const float4*)&sw[(16+m)*PADS + kg*8 + 4];
        *(float4*)&x[8]  = *(const float4*)&sw[(16+m)*PADS + 32 + kg*8];
        *(float4*)&x[12] = *(const float4*)&sw[(16+m)*PADS + 32 + kg*8 + 4];
        split8(&x[0], ah1[0], al1[0]);
        split8(&x[8], ah1[1], al1[1]);
    }
    __builtin_amdgcn_wave_barrier();
}

// Persistent waves: each of the 4096 waves owns GQ or GQ+1 CONTIGUOUS 32-edge groups
// of the dst-sorted edge list. Interior segments (node fully inside the wave's window)
// have a sole writer -> plain coalesced store; only first/last segments use atomicAdd.
__global__ __launch_bounds__(256, 3)
void edge_kernel(const float* __restrict__ Eg,
                 const int* __restrict__ src, const int* __restrict__ dst,
                 const int* __restrict__ eidx,
                 const short* __restrict__ WF,
                 const float* __restrict__ b1, const float* __restrict__ b2,
                 const float* __restrict__ bB, const float* __restrict__ bC,
                 const float* __restrict__ Vp,
                 float* __restrict__ S1, float* __restrict__ S2)
{
    __shared__ float scratch[4 * 32 * PADS];   // per-wave 32x68 fp32 tiles (34816 B)
    __shared__ int aux[4 * 64];                // per-wave: [0..31]=src, [32..63]=dst

    const int tid = threadIdx.x;
    const int lane = tid & 63, wv = tid >> 6;
    float* sw = scratch + wv * 32 * PADS;
    int* auxw = aux + wv * 64;

    const int gw = blockIdx.x * 4 + wv;        // global wave id 0..4095
    int g0, gn;
    if (gw < GR) { g0 = gw * (GQ + 1); gn = GQ + 1; }
    else         { g0 = GR * (GQ + 1) + (gw - GR) * GQ; gn = GQ; }

    const int m = lane & 15, kg = lane >> 4;
    const int n = lane & 15, mg = lane >> 4;
    const int f = lane;

    float s1 = 0.f, s2 = 0.f;
    int prev = -1;
    int seg_atomic = 1;                        // first segment of window may span into prev window

    for (int g = 0; g < gn; ++g) {
        const int ew = (g0 + g) * 32;          // this group's 32 edges (dst-sorted)

        // stage: indices for all 32 edges
        if (lane < 32) {
            int eg = eidx[ew + lane];
            auxw[lane]      = src[eg];
            auxw[32 + lane] = dst[eg];
        }
        // A-fragments straight from gathered E rows (no LDS)
        bf16x8 ah0[2], al0[2], ah1[2], al1[2];
        {
            int eg0 = eidx[ew + m];
            int eg1 = eidx[ew + 16 + m];
            const float* er0 = Eg + (size_t)eg0*DDIM + kg*8;
            const float* er1 = Eg + (size_t)eg1*DDIM + kg*8;
            float x[16];
            *(float4*)&x[0]  = *(const float4*)&er0[0];
            *(float4*)&x[4]  = *(const float4*)&er0[4];
            *(float4*)&x[8]  = *(const float4*)&er0[32];
            *(float4*)&x[12] = *(const float4*)&er0[36];
            split8(&x[0], ah0[0], al0[0]);
            split8(&x[8], ah0[1], al0[1]);
            *(float4*)&x[0]  = *(const float4*)&er1[0];
            *(float4*)&x[4]  = *(const float4*)&er1[4];
            *(float4*)&x[8]  = *(const float4*)&er1[32];
            *(float4*)&x[12] = *(const float4*)&er1[36];
            split8(&x[0], ah1[0], al1[0]);
            split8(&x[8], ah1[1], al1[1]);
        }

        // layer 1
        f32x4 acc0[4], acc1[4];
        #pragma unroll
        for (int t = 0; t < 4; ++t) { acc0[t] = (f32x4){0.f,0.f,0.f,0.f}; acc1[t] = (f32x4){0.f,0.f,0.f,0.f}; }
        gemm64_dual(WF, lane, ah0, al0, ah1, al1, acc0, acc1);
        #pragma unroll
        for (int t = 0; t < 4; ++t) {
            float b = b1[t*16 + n];
            #pragma unroll
            for (int r = 0; r < 4; ++r) {
                acc0[t][r] = fmaxf(acc0[t][r] + b, 0.0f);
                acc1[t][r] = fmaxf(acc1[t][r] + b, 0.0f);
            }
        }
        transpose_frags_dual(sw, acc0, acc1, lane, ah0, al0, ah1, al1);

        // layer 2
        #pragma unroll
        for (int t = 0; t < 4; ++t) { acc0[t] = (f32x4){0.f,0.f,0.f,0.f}; acc1[t] = (f32x4){0.f,0.f,0.f,0.f}; }
        gemm64_dual(WF + 8192, lane, ah0, al0, ah1, al1, acc0, acc1);
        #pragma unroll
        for (int t = 0; t < 4; ++t) {
            float b = b2[t*16 + n];
            #pragma unroll
            for (int r = 0; r < 4; ++r) {
                acc0[t][r] = fmaxf(acc0[t][r] + b, 0.0f);
                acc1[t][r] = fmaxf(acc1[t][r] + b, 0.0f);
            }
        }
        transpose_frags_dual(sw, acc0, acc1, lane, ah0, al0, ah1, al1);   // a-frags = x2

        // scale + shift heads (same A operand, shared B-frags per head)
        f32x4 accS0[4], accS1[4], accH0[4], accH1[4];
        #pragma unroll
        for (int t = 0; t < 4; ++t) {
            accS0[t] = (f32x4){0.f,0.f,0.f,0.f}; accS1[t] = (f32x4){0.f,0.f,0.f,0.f};
            accH0[t] = (f32x4){0.f,0.f,0.f,0.f}; accH1[t] = (f32x4){0.f,0.f,0.f,0.f};
        }
        gemm64_dual(WF + 2*8192, lane, ah0, al0, ah1, al1, accS0, accS1);
        gemm64_dual(WF + 3*8192, lane, ah0, al0, ah1, al1, accH0, accH1);

        // message phase in D-layout registers: lane owns f=t*16+n, local edge e=(tile*16)+mg*4+r
        {
            int sn0[4], sn1[4];
            #pragma unroll
            for (int r = 0; r < 4; ++r) { sn0[r] = auxw[mg*4 + r]; sn1[r] = auxw[16 + mg*4 + r]; }
            #pragma unroll
            for (int t = 0; t < 4; ++t) {
                const int ff = t*16 + n;
                const float bBv = bB[ff];
                const float bCv = bC[ff];
                #pragma unroll
                for (int r = 0; r < 4; ++r) {
                    float vp0 = Vp[(size_t)sn0[r]*DDIM + ff];
                    float sg0 = 1.0f / (1.0f + __expf(-(accS0[t][r] + bBv)));
                    sw[(mg*4 + r)*PADS + ff] = fmaf(sg0, vp0, accH0[t][r] + bCv);
                    float vp1 = Vp[(size_t)sn1[r]*DDIM + ff];
                    float sg1 = 1.0f / (1.0f + __expf(-(accS1[t][r] + bBv)));
                    sw[(16 + mg*4 + r)*PADS + ff] = fmaf(sg1, vp1, accH1[t][r] + bCv);
                }
            }
        }
        __builtin_amdgcn_wave_barrier();

        // per-wave segmented reduction with cross-group carry: lane = feature (0..63)
        #pragma unroll 4
        for (int e = 0; e < 32; ++e) {
            int dn = auxw[32 + e];
            float m1 = sw[e*PADS + f];
            float m2 = m1 * m1;
            if (dn != prev) {
                if (prev >= 0) {
                    if (seg_atomic) {
                        atomicAdd(&S1[(size_t)prev*DDIM + f], s1);
                        atomicAdd(&S2[(size_t)prev*DDIM + f], s2);
                    } else {
                        S1[(size_t)prev*DDIM + f] = s1;   // sole writer (interior segment)
                        S2[(size_t)prev*DDIM + f] = s2;
                    }
                    seg_atomic = 0;   // subsequent segments start strictly inside window
                }
                s1 = 0.f; s2 = 0.f; prev = dn;
            }
            s1 += m1; s2 += m2;
        }
        __builtin_amdgcn_wave_barrier();
    }
    // final segment may extend into the next wave's window -> always atomic
    if (prev >= 0) {
        atomicAdd(&S1[(size_t)prev*DDIM + f], s1);
        atomicAdd(&S2[(size_t)prev*DDIM + f], s2);
    }
}

// ---------------- finalize ----------------
__global__ __launch_bounds__(256)
void finalize_kernel(const float* __restrict__ S1, const float* __restrict__ S2,
                     const int* __restrict__ degi, float* __restrict__ out)
{
    int gid = blockIdx.x * blockDim.x + threadIdx.x;
    if (gid >= NN*DDIM) return;
    int n = gid >> 6;
    float dn = (float)degi[n];
    dn = dn > 1.0f ? dn : 1.0f;
    float v = (S2[gid] - S1[gid]) / dn;
    out[gid] = sqrtf(fmaxf(v, 0.0f) + EPS_V);
}

extern "C" void kernel_launch(void* const* d_in, const int* in_sizes, int n_in,
                              void* d_out, int out_size, void* d_ws, size_t ws_size,
                              hipStream_t stream) {
    const float* V   = (const float*)d_in[0];
    const float* Eg  = (const float*)d_in[1];
    const int*   src = (const int*)d_in[2];
    const int*   dst = (const int*)d_in[3];
    const float* pAw = (const float*)d_in[4];
    const float* pAb = (const float*)d_in[5];
    const float* pBw = (const float*)d_in[6];
    const float* pBb = (const float*)d_in[7];
    const float* mW1 = (const float*)d_in[8];
    const float* mb1 = (const float*)d_in[9];
    const float* mW2 = (const float*)d_in[10];
    const float* mb2 = (const float*)d_in[11];
    const float* BW  = (const float*)d_in[12];
    const float* Bb  = (const float*)d_in[13];
    const float* CW  = (const float*)d_in[14];
    const float* Cb  = (const float*)d_in[15];
    float* out = (float*)d_out;

    float* ws    = (float*)d_ws;
    float* Vp    = ws;                                   // NN*DDIM f32
    float* S1    = ws + (size_t)NN*DDIM;                 // NN*DDIM f32
    float* S2    = ws + (size_t)2*NN*DDIM;               // NN*DDIM f32
    int*   degi  = (int*)(ws + (size_t)3*NN*DDIM);       // NN i32
    int*   curs  = degi + NN;                            // NN i32
    int*   linc  = curs + NN;                            // NN i32
    int*   bsum  = linc + NN;                            // NB_SCAN i32
    int*   bbase = bsum + NB_SCAN;                       // NB_SCAN i32 (layout keep)
    int*   eidx  = bbase + NB_SCAN;                      // NE i32
    short* WF    = (short*)(eidx + NE);                  // 4*8192 shorts (64 KB)

    hipMemsetAsync(S1, 0, (size_t)(2*NN*DDIM + NN) * sizeof(float), stream);

    prep_w_kernel<<<64, 256, 0, stream>>>(mW1, mW2, BW, CW, WF);
    node_pool_kernel<<<(NN + 63)/64, 256, 0, stream>>>(V, pAw, pAb, pBw, pBb, Vp, dst, degi);
    scan1_kernel<<<NB_SCAN, 256, 0, stream>>>(degi, linc, bsum);
    scan23_kernel<<<NB_SCAN, 256, 0, stream>>>(degi, linc, bsum, curs);
    scatter_kernel<<<(NE + 255)/256, 256, 0, stream>>>(dst, curs, eidx);
    edge_kernel<<<NWAVES_E/4, 256, 0, stream>>>(Eg, src, dst, eidx, WF,
                                                mb1, mb2, Bb, Cb, Vp, S1, S2);
    finalize_kernel<<<(NN*DDIM + 255)/256, 256, 0, stream>>>(S1, S2, degi, out);
}

// Round 5
// 597.483 us; speedup vs baseline: 1.3190x; 1.3190x over previous
//
#include <hip/hip_runtime.h>

#define NN 50000
#define NE 800000
#define DDIM 64
#define PADX 68          // fp32 LDS row stride (node pool)
#define PADS 68          // fp32 per-wave scratch stride (rows are 272 B -> 16B aligned, odd*4 banks)
#define NB_SCAN ((NN + 255) / 256)   // 196
#define NEG_SLOPE 0.2f
#define EPS_V 1e-5f

typedef short bf16x8 __attribute__((ext_vector_type(8)));
typedef float f32x4 __attribute__((ext_vector_type(4)));

__device__ __forceinline__ float lrelu_f(float x) { return x >= 0.0f ? x : NEG_SLOPE * x; }

__device__ __forceinline__ unsigned short bf16_rn(float x) {
    union { float f; unsigned int u; } c; c.f = x;
    unsigned int r = c.u + 0x7FFF + ((c.u >> 16) & 1);
    return (unsigned short)(r >> 16);
}
__device__ __forceinline__ float bf16_tof(unsigned short h) {
    union { float f; unsigned int u; } c; c.u = ((unsigned int)h) << 16;
    return c.f;
}

// packed bf16 convert (RNE), 2 f32 -> u32 [lo=bf16(a) | hi=bf16(b)]
__device__ __forceinline__ unsigned cvtpk_bf16(float a, float b) {
    unsigned r;
    asm("v_cvt_pk_bf16_f32 %0, %1, %2" : "=v"(r) : "v"(a), "v"(b));
    return r;
}

// split 8 fp32 -> hi/lo bf16x8 (RNE both; ~2^-18 effective rel err) via v_cvt_pk_bf16_f32
__device__ __forceinline__ void split8(const float* __restrict__ v, bf16x8& h, bf16x8& l)
{
    union { bf16x8 v8; unsigned u[4]; } H, L;
    #pragma unroll
    for (int k = 0; k < 4; ++k) {
        float a = v[2*k], b = v[2*k+1];
        unsigned p = cvtpk_bf16(a, b);
        union { float f; unsigned u; } h0, h1;
        h0.u = p << 16;
        h1.u = p & 0xFFFF0000u;
        unsigned q = cvtpk_bf16(a - h0.f, b - h1.f);
        H.u[k] = p;
        L.u[k] = q;
    }
    h = H.v8; l = L.v8;
}

// ---------------- fp32 micro-tile GEMM helpers (node pooling only) ----------------
__device__ __forceinline__ void mma_tile(float acc[16], const float* __restrict__ XT,
                                         const float* __restrict__ Wc, int e0, int f0)
{
    #pragma unroll 4
    for (int kk = 0; kk < DDIM; kk += 4) {
        float4 A0 = *(const float4*)&XT[(kk+0)*PADX + e0];
        float4 A1 = *(const float4*)&XT[(kk+1)*PADX + e0];
        float4 A2 = *(const float4*)&XT[(kk+2)*PADX + e0];
        float4 A3 = *(const float4*)&XT[(kk+3)*PADX + e0];
        float4 B0 = *(const float4*)&Wc[(f0+0)*PADX + kk];
        float4 B1 = *(const float4*)&Wc[(f0+1)*PADX + kk];
        float4 B2 = *(const float4*)&Wc[(f0+2)*PADX + kk];
        float4 B3 = *(const float4*)&Wc[(f0+3)*PADX + kk];
        const float a[4][4] = {{A0.x,A0.y,A0.z,A0.w},{A1.x,A1.y,A1.z,A1.w},
                               {A2.x,A2.y,A2.z,A2.w},{A3.x,A3.y,A3.z,A3.w}};
        const float b[4][4] = {{B0.x,B0.y,B0.z,B0.w},{B1.x,B1.y,B1.z,B1.w},
                               {B2.x,B2.y,B2.z,B2.w},{B3.x,B3.y,B3.z,B3.w}};
        #pragma unroll
        for (int j = 0; j < 4; ++j)
            #pragma unroll
            for (int i = 0; i < 4; ++i)
                #pragma unroll
                for (int q = 0; q < 4; ++q)
                    acc[i*4+j] = fmaf(a[q][i], b[j][q], acc[i*4+j]);
    }
}

__device__ __forceinline__ void load_w_f32(float* __restrict__ Wc, const float* __restrict__ Wg, int tid)
{
    #pragma unroll
    for (int c = 0; c < 4; ++c) {
        int idx = (c << 10) + (tid << 2);
        int f = idx >> 6, k = idx & 63;
        *(float4*)&Wc[f*PADX + k] = *(const float4*)&Wg[idx];
    }
}

// ---------------- node pooling (fp32) + fused dst histogram ----------------
__global__ __launch_bounds__(256, 3)
void node_pool_kernel(const float* __restrict__ V,
                      const float* __restrict__ Aw, const float* __restrict__ Ab,
                      const float* __restrict__ Bw, const float* __restrict__ Bbv,
                      float* __restrict__ Vp,
                      const int* __restrict__ dst, int* __restrict__ degi)
{
    __shared__ float Wc[DDIM*PADX];
    __shared__ float XT[DDIM*PADX];
    const int tid = threadIdx.x;
    const int nb = blockIdx.x * 64;
    const int e0 = (tid & 15) << 2;
    const int f0 = (tid >> 4) << 2;

    #pragma unroll
    for (int c = 0; c < 4; ++c) {
        int idx = (c << 10) + (tid << 2);
        int e = idx >> 6, d = idx & 63;
        int row = nb + e; if (row > NN-1) row = NN-1;
        float4 v = *(const float4*)&V[(size_t)row*DDIM + d];
        XT[(d+0)*PADX + e] = lrelu_f(v.x);
        XT[(d+1)*PADX + e] = lrelu_f(v.y);
        XT[(d+2)*PADX + e] = lrelu_f(v.z);
        XT[(d+3)*PADX + e] = lrelu_f(v.w);
    }
    load_w_f32(Wc, Aw, tid);
    __syncthreads();

    float acc[16];
    #pragma unroll
    for (int i = 0; i < 16; ++i) acc[i] = 0.f;
    mma_tile(acc, XT, Wc, e0, f0);
    __syncthreads();

    {   // lrelu(acc + Ab) -> XT
        float4 bv = *(const float4*)&Ab[f0];
        const float ba[4] = {bv.x, bv.y, bv.z, bv.w};
        #pragma unroll
        for (int j = 0; j < 4; ++j) {
            float4 v;
            v.x = lrelu_f(acc[0*4+j] + ba[j]);
            v.y = lrelu_f(acc[1*4+j] + ba[j]);
            v.z = lrelu_f(acc[2*4+j] + ba[j]);
            v.w = lrelu_f(acc[3*4+j] + ba[j]);
            *(float4*)&XT[(f0+j)*PADX + e0] = v;
        }
    }
    load_w_f32(Wc, Bw, tid);
    __syncthreads();

    float acc2[16];
    #pragma unroll
    for (int i = 0; i < 16; ++i) acc2[i] = 0.f;
    mma_tile(acc2, XT, Wc, e0, f0);

    float4 bv = *(const float4*)&Bbv[f0];
    #pragma unroll
    for (int i = 0; i < 4; ++i) {
        int row = nb + e0 + i;
        if (row < NN) {
            float4 o;
            o.x = acc2[i*4+0] + bv.x;
            o.y = acc2[i*4+1] + bv.y;
            o.z = acc2[i*4+2] + bv.z;
            o.w = acc2[i*4+3] + bv.w;
            *(float4*)&Vp[(size_t)row*DDIM + f0] = o;
        }
    }

    // fused histogram tail: grid-stride over edges
    const int stride = gridDim.x * 256;
    for (int e = blockIdx.x * 256 + tid; e < NE; e += stride)
        atomicAdd(&degi[dst[e]], 1);
}

// ---------------- split-bf16 weight fragment precompute ----------------
// Layout: WF[L][t][ks][hl][lane][j] shorts; per-layer stride 8192 shorts.
// lane: n=lane&15 (feature col), kg=lane>>4; f=t*16+n; k=ks*32+kg*8+j.
__global__ __launch_bounds__(256)
void prep_w_kernel(const float* __restrict__ W1, const float* __restrict__ W2,
                   const float* __restrict__ WB, const float* __restrict__ WC,
                   short* __restrict__ WF)
{
    int gid = blockIdx.x * 256 + threadIdx.x;   // grid = 64 blocks -> 16384 threads
    int L = gid >> 12, r = gid & 4095;
    int t = r >> 10, ks = (r >> 9) & 1, lane = (r >> 3) & 63, j = r & 7;
    const float* Ws = (L == 0) ? W1 : (L == 1) ? W2 : (L == 2) ? WB : WC;
    int n = lane & 15, kg = lane >> 4;
    int f = t*16 + n, k = ks*32 + kg*8 + j;
    float v = Ws[f*64 + k];
    unsigned short h = bf16_rn(v);
    unsigned short l = bf16_rn(v - bf16_tof(h));
    int base = L*8192 + ((t*2 + ks)*2)*512 + lane*8 + j;
    WF[base]       = (short)h;
    WF[base + 512] = (short)l;
}

// ---------------- CSR build: scan / scatter ----------------
__global__ __launch_bounds__(256)
void scan1_kernel(const int* __restrict__ degi, int* __restrict__ linc, int* __restrict__ bsum)
{
    __shared__ int ws[4];
    const int tid = threadIdx.x;
    const int lane = tid & 63, wv = tid >> 6;
    int i = blockIdx.x * 256 + tid;
    int v = (i < NN) ? degi[i] : 0;
    int sc = v;
    #pragma unroll
    for (int off = 1; off < 64; off <<= 1) {
        int t = __shfl_up(sc, off, 64);
        if (lane >= off) sc += t;
    }
    if (lane == 63) ws[wv] = sc;
    __syncthreads();
    int wb = 0;
    #pragma unroll
    for (int w = 0; w < 4; ++w) if (w < wv) wb += ws[w];
    int incl = sc + wb;
    if (i < NN) linc[i] = incl;
    if (tid == 255) bsum[blockIdx.x] = incl;
}

__global__ __launch_bounds__(256)
void scan23_kernel(const int* __restrict__ degi, const int* __restrict__ linc,
                   const int* __restrict__ bsum, int* __restrict__ curs)
{
    __shared__ int ws[4];
    __shared__ int base_s;
    const int tid = threadIdx.x;
    const int lane = tid & 63, wv = tid >> 6;
    int v = (tid < NB_SCAN) ? bsum[tid] : 0;
    int sc = v;
    #pragma unroll
    for (int off = 1; off < 64; off <<= 1) {
        int t = __shfl_up(sc, off, 64);
        if (lane >= off) sc += t;
    }
    if (lane == 63) ws[wv] = sc;
    __syncthreads();
    int wb = 0;
    #pragma unroll
    for (int w = 0; w < 4; ++w) if (w < wv) wb += ws[w];
    if (tid == blockIdx.x) base_s = sc + wb - v;
    __syncthreads();
    int i = blockIdx.x * 256 + tid;
    if (i < NN) curs[i] = base_s + linc[i] - degi[i];
}

// scatter: compute inverse permutation pinv[e] = sorted position of edge e.
// After this kernel, curs[n] = global END offset of node n's segment.
__global__ __launch_bounds__(256)
void scatter_kernel(const int* __restrict__ dst, int* __restrict__ cursor, int* __restrict__ pinv)
{
    int e = blockIdx.x * 256 + threadIdx.x;
    if (e < NE) {
        pinv[e] = atomicAdd(&cursor[dst[e]], 1);
    }
}

// ---------------- natural-order split-bf16 MFMA edge MLP + message ----------------
// Dual-tile GEMM: weight fragments loaded ONCE per (ks) serve both 16-row tiles.
__device__ __forceinline__ void gemm64_dual(const short* __restrict__ WL, int lane,
                                            const bf16x8 ah0[2], const bf16x8 al0[2],
                                            const bf16x8 ah1[2], const bf16x8 al1[2],
                                            f32x4 acc0[4], f32x4 acc1[4])
{
    #pragma unroll
    for (int ks = 0; ks < 2; ++ks) {
        bf16x8 bh[4], bl[4];
        #pragma unroll
        for (int t = 0; t < 4; ++t) {
            bh[t] = *(const bf16x8*)&WL[(((t*2 + ks)*2 + 0)*64 + lane)*8];
            bl[t] = *(const bf16x8*)&WL[(((t*2 + ks)*2 + 1)*64 + lane)*8];
        }
        #pragma unroll
        for (int t = 0; t < 4; ++t) {
            acc0[t] = __builtin_amdgcn_mfma_f32_16x16x32_bf16(al0[ks], bh[t], acc0[t], 0, 0, 0);
            acc1[t] = __builtin_amdgcn_mfma_f32_16x16x32_bf16(al1[ks], bh[t], acc1[t], 0, 0, 0);
            acc0[t] = __builtin_amdgcn_mfma_f32_16x16x32_bf16(ah0[ks], bl[t], acc0[t], 0, 0, 0);
            acc1[t] = __builtin_amdgcn_mfma_f32_16x16x32_bf16(ah1[ks], bl[t], acc1[t], 0, 0, 0);
            acc0[t] = __builtin_amdgcn_mfma_f32_16x16x32_bf16(ah0[ks], bh[t], acc0[t], 0, 0, 0);
            acc1[t] = __builtin_amdgcn_mfma_f32_16x16x32_bf16(ah1[ks], bh[t], acc1[t], 0, 0, 0);
        }
    }
}

// D-layout y[t][r] for both tiles -> per-wave 32-row LDS -> A-frags for next layer.
// Wave-lockstep: DS ops from one wave complete in order; no __syncthreads needed.
__device__ __forceinline__ void transpose_frags_dual(float* __restrict__ sw,
                                                     const f32x4 y0[4], const f32x4 y1[4],
                                                     int lane,
                                                     bf16x8 ah0[2], bf16x8 al0[2],
                                                     bf16x8 ah1[2], bf16x8 al1[2])
{
    const int n = lane & 15, mg = lane >> 4;
    #pragma unroll
    for (int t = 0; t < 4; ++t)
        #pragma unroll
        for (int r = 0; r < 4; ++r) {
            sw[(mg*4 + r)*PADS + t*16 + n]      = y0[t][r];
            sw[(16 + mg*4 + r)*PADS + t*16 + n] = y1[t][r];
        }
    __builtin_amdgcn_wave_barrier();
    const int m = lane & 15, kg = lane >> 4;   // m: edge row, kg: k-group
    {
        float x[16];
        *(float4*)&x[0]  = *(const float4*)&sw[m*PADS + kg*8];
        *(float4*)&x[4]  = *(const float4*)&sw[m*PADS + kg*8 + 4];
        *(float4*)&x[8]  = *(const float4*)&sw[m*PADS + 32 + kg*8];
        *(float4*)&x[12] = *(const float4*)&sw[m*PADS + 32 + kg*8 + 4];
        split8(&x[0], ah0[0], al0[0]);
        split8(&x[8], ah0[1], al0[1]);
    }
    {
        float x[16];
        *(float4*)&x[0]  = *(const float4*)&sw[(16+m)*PADS + kg*8];
        *(float4*)&x[4]  = *(const float4*)&sw[(16+m)*PADS + kg*8 + 4];
        *(float4*)&x[8]  = *(const float4*)&sw[(16+m)*PADS + 32 + kg*8];
        *(float4*)&x[12] = *(const float4*)&sw[(16+m)*PADS + 32 + kg*8 + 4];
        split8(&x[0], ah1[0], al1[0]);
        split8(&x[8], ah1[1], al1[1]);
    }
    __builtin_amdgcn_wave_barrier();
}

// E1: natural edge order. Coalesced E reads, MLP+heads+message, write message row
// to its dst-sorted position pinv[e]. No atomics, no eidx gather.
__global__ __launch_bounds__(256, 3)
void e1_mlp_kernel(const float* __restrict__ Eg,
                   const int* __restrict__ src, const int* __restrict__ pinv,
                   const short* __restrict__ WF,
                   const float* __restrict__ b1, const float* __restrict__ b2,
                   const float* __restrict__ bB, const float* __restrict__ bC,
                   const float* __restrict__ Vp,
                   float* __restrict__ M1s)
{
    __shared__ float scratch[4 * 32 * PADS];   // per-wave 32x68 fp32 tiles (34816 B)
    __shared__ int aux[4 * 64];                // per-wave: [0..31]=pinv, [32..63]=src

    const int tid = threadIdx.x;
    const int lane = tid & 63, wv = tid >> 6;
    float* sw = scratch + wv * 32 * PADS;
    int* auxw = aux + wv * 64;

    const int e0 = blockIdx.x * 128 + wv * 32;  // this wave's 32 edges (natural order)
    const int m = lane & 15, kg = lane >> 4;
    const int n = lane & 15, mg = lane >> 4;

    if (lane < 32) {
        auxw[lane]      = pinv[e0 + lane];
        auxw[32 + lane] = src[e0 + lane];
    }
    // A-fragments straight from CONSECUTIVE E rows (streaming, no gather)
    bf16x8 ah0[2], al0[2], ah1[2], al1[2];
    {
        const float* er0 = Eg + (size_t)(e0 + m)*DDIM + kg*8;
        const float* er1 = Eg + (size_t)(e0 + 16 + m)*DDIM + kg*8;
        float x[16];
        *(float4*)&x[0]  = *(const float4*)&er0[0];
        *(float4*)&x[4]  = *(const float4*)&er0[4];
        *(float4*)&x[8]  = *(const float4*)&er0[32];
        *(float4*)&x[12] = *(const float4*)&er0[36];
        split8(&x[0], ah0[0], al0[0]);
        split8(&x[8], ah0[1], al0[1]);
        *(float4*)&x[0]  = *(const float4*)&er1[0];
        *(float4*)&x[4]  = *(const float4*)&er1[4];
        *(float4*)&x[8]  = *(const float4*)&er1[32];
        *(float4*)&x[12] = *(const float4*)&er1[36];
        split8(&x[0], ah1[0], al1[0]);
        split8(&x[8], ah1[1], al1[1]);
    }

    // layer 1
    f32x4 acc0[4], acc1[4];
    #pragma unroll
    for (int t = 0; t < 4; ++t) { acc0[t] = (f32x4){0.f,0.f,0.f,0.f}; acc1[t] = (f32x4){0.f,0.f,0.f,0.f}; }
    gemm64_dual(WF, lane, ah0, al0, ah1, al1, acc0, acc1);
    #pragma unroll
    for (int t = 0; t < 4; ++t) {
        float b = b1[t*16 + n];
        #pragma unroll
        for (int r = 0; r < 4; ++r) {
            acc0[t][r] = fmaxf(acc0[t][r] + b, 0.0f);
            acc1[t][r] = fmaxf(acc1[t][r] + b, 0.0f);
        }
    }
    transpose_frags_dual(sw, acc0, acc1, lane, ah0, al0, ah1, al1);

    // layer 2
    #pragma unroll
    for (int t = 0; t < 4; ++t) { acc0[t] = (f32x4){0.f,0.f,0.f,0.f}; acc1[t] = (f32x4){0.f,0.f,0.f,0.f}; }
    gemm64_dual(WF + 8192, lane, ah0, al0, ah1, al1, acc0, acc1);
    #pragma unroll
    for (int t = 0; t < 4; ++t) {
        float b = b2[t*16 + n];
        #pragma unroll
        for (int r = 0; r < 4; ++r) {
            acc0[t][r] = fmaxf(acc0[t][r] + b, 0.0f);
            acc1[t][r] = fmaxf(acc1[t][r] + b, 0.0f);
        }
    }
    transpose_frags_dual(sw, acc0, acc1, lane, ah0, al0, ah1, al1);   // a-frags = x2

    // scale + shift heads (same A operand, shared B-frags per head)
    f32x4 accS0[4], accS1[4], accH0[4], accH1[4];
    #pragma unroll
    for (int t = 0; t < 4; ++t) {
        accS0[t] = (f32x4){0.f,0.f,0.f,0.f}; accS1[t] = (f32x4){0.f,0.f,0.f,0.f};
        accH0[t] = (f32x4){0.f,0.f,0.f,0.f}; accH1[t] = (f32x4){0.f,0.f,0.f,0.f};
    }
    gemm64_dual(WF + 2*8192, lane, ah0, al0, ah1, al1, accS0, accS1);
    gemm64_dual(WF + 3*8192, lane, ah0, al0, ah1, al1, accH0, accH1);

    // message phase in D-layout registers: lane owns f=t*16+n, local edge e=(tile*16)+mg*4+r
    {
        int sn0[4], sn1[4];
        #pragma unroll
        for (int r = 0; r < 4; ++r) { sn0[r] = auxw[32 + mg*4 + r]; sn1[r] = auxw[32 + 16 + mg*4 + r]; }
        #pragma unroll
        for (int t = 0; t < 4; ++t) {
            const int ff = t*16 + n;
            const float bBv = bB[ff];
            const float bCv = bC[ff];
            #pragma unroll
            for (int r = 0; r < 4; ++r) {
                float vp0 = Vp[(size_t)sn0[r]*DDIM + ff];
                float sg0 = 1.0f / (1.0f + __expf(-(accS0[t][r] + bBv)));
                sw[(mg*4 + r)*PADS + ff] = fmaf(sg0, vp0, accH0[t][r] + bCv);
                float vp1 = Vp[(size_t)sn1[r]*DDIM + ff];
                float sg1 = 1.0f / (1.0f + __expf(-(accS1[t][r] + bBv)));
                sw[(16 + mg*4 + r)*PADS + ff] = fmaf(sg1, vp1, accH1[t][r] + bCv);
            }
        }
    }
    __builtin_amdgcn_wave_barrier();

    // store each message row to its sorted position: 256B fully-coalesced rows
    #pragma unroll 4
    for (int r = 0; r < 32; ++r) {
        int p = auxw[r];
        M1s[(size_t)p*DDIM + lane] = sw[r*PADS + lane];
    }
}

// E2: CSR reduce, one wave per node. Contiguous coalesced reads, no atomics,
// finalize fused (sqrt(relu((S2-S1)/deg)+eps)).
// cend = curs AFTER scatter: cend[n] = global end offset of node n's segment.
__global__ __launch_bounds__(256)
void e2_reduce_kernel(const float* __restrict__ M1s,
                      const int* __restrict__ cend, const int* __restrict__ degi,
                      float* __restrict__ out)
{
    const int nw = blockIdx.x * 4 + (threadIdx.x >> 6);  // node id
    if (nw >= NN) return;
    const int lane = threadIdx.x & 63;
    const int deg = degi[nw];
    const int start = cend[nw] - deg;
    const float* base = M1s + (size_t)start*DDIM + lane;
    float s1 = 0.f, s2 = 0.f;
    int i = 0;
    for (; i + 4 <= deg; i += 4) {
        float a = base[(size_t)(i+0)*DDIM];
        float b = base[(size_t)(i+1)*DDIM];
        float c = base[(size_t)(i+2)*DDIM];
        float d = base[(size_t)(i+3)*DDIM];
        s1 += a + b + c + d;
        s2 = fmaf(a, a, s2); s2 = fmaf(b, b, s2);
        s2 = fmaf(c, c, s2); s2 = fmaf(d, d, s2);
    }
    for (; i < deg; ++i) {
        float a = base[(size_t)i*DDIM];
        s1 += a;
        s2 = fmaf(a, a, s2);
    }
    float dn = deg > 1 ? (float)deg : 1.0f;
    float v = (s2 - s1) / dn;
    out[(size_t)nw*DDIM + lane] = sqrtf(fmaxf(v, 0.0f) + EPS_V);
}

extern "C" void kernel_launch(void* const* d_in, const int* in_sizes, int n_in,
                              void* d_out, int out_size, void* d_ws, size_t ws_size,
                              hipStream_t stream) {
    const float* V   = (const float*)d_in[0];
    const float* Eg  = (const float*)d_in[1];
    const int*   src = (const int*)d_in[2];
    const int*   dst = (const int*)d_in[3];
    const float* pAw = (const float*)d_in[4];
    const float* pAb = (const float*)d_in[5];
    const float* pBw = (const float*)d_in[6];
    const float* pBb = (const float*)d_in[7];
    const float* mW1 = (const float*)d_in[8];
    const float* mb1 = (const float*)d_in[9];
    const float* mW2 = (const float*)d_in[10];
    const float* mb2 = (const float*)d_in[11];
    const float* BW  = (const float*)d_in[12];
    const float* Bb  = (const float*)d_in[13];
    const float* CW  = (const float*)d_in[14];
    const float* Cb  = (const float*)d_in[15];
    float* out = (float*)d_out;

    float* ws    = (float*)d_ws;
    float* Vp    = ws;                                   // NN*DDIM f32 (3.2e6)
    int*   degi  = (int*)(ws + (size_t)NN*DDIM);         // NN i32
    int*   curs  = degi + NN;                            // NN i32
    int*   linc  = curs + NN;                            // NN i32
    int*   bsum  = linc + NN;                            // NB_SCAN i32
    int*   pinv  = bsum + NB_SCAN;                       // NE i32
    short* WF    = (short*)(pinv + NE);                  // 4*8192 shorts (64 KB)
    float* M1s   = (float*)(WF + 4*8192);                // NE*DDIM f32 (204.8 MB)

    hipMemsetAsync(degi, 0, (size_t)NN * sizeof(int), stream);

    prep_w_kernel<<<64, 256, 0, stream>>>(mW1, mW2, BW, CW, WF);
    node_pool_kernel<<<(NN + 63)/64, 256, 0, stream>>>(V, pAw, pAb, pBw, pBb, Vp, dst, degi);
    scan1_kernel<<<NB_SCAN, 256, 0, stream>>>(degi, linc, bsum);
    scan23_kernel<<<NB_SCAN, 256, 0, stream>>>(degi, linc, bsum, curs);
    scatter_kernel<<<(NE + 255)/256, 256, 0, stream>>>(dst, curs, pinv);
    e1_mlp_kernel<<<NE/128, 256, 0, stream>>>(Eg, src, pinv, WF,
                                              mb1, mb2, Bb, Cb, Vp, M1s);
    // after scatter, curs[n] = end offset of node n's CSR segment
    e2_reduce_kernel<<<(NN + 3)/4, 256, 0, stream>>>(M1s, curs, degi, out);
}